// Round 5
// baseline (365.056 us; speedup 1.0000x reference)
//
#include <hip/hip_runtime.h>
#include <stdint.h>

#define NN 100000
#define NE 1600000
#define DD 128
#define NTILES ((NN + 127) / 128)   // 782
#define NBUCK ((NN + 255) / 256)    // 391 node-scan blocks
#define NCNT (NBUCK * 256)          // 100,096 padded counters

typedef __bf16 bf16x8 __attribute__((ext_vector_type(8)));
typedef float f32x4 __attribute__((ext_vector_type(4)));
typedef float f32x2 __attribute__((ext_vector_type(2)));

// round-to-nearest-even fp32 -> bf16, two at a time, packed into a uint
__device__ __forceinline__ unsigned int f2bf2(float a, float b) {
  union { float f; unsigned u; } x, y;
  x.f = a; y.f = b;
  unsigned ua = x.u + (0x7FFFu + ((x.u >> 16) & 1u));
  unsigned ub = y.u + (0x7FFFu + ((y.u >> 16) & 1u));
  return (ua >> 16) | (ub & 0xFFFF0000u);
}

// ---------------- 00. zero per-node counters (workspace arrives poisoned) ---
__global__ __launch_bounds__(256) void zero_kernel(int* __restrict__ cnt) {
  cnt[blockIdx.x * 256 + threadIdx.x] = 0;   // NCNT threads exactly
}

// ---------------- 0+A1. h -> h8 (fp8) + hbf (bf16 fragment order) + hist ----
// Block b covers rows b*16 .. b*16+15 (6250*16 = 100,000 exactly).
// Additionally each block histograms 256 edges (6250*256 = 1.6M exactly)
// with one global atomicAdd per thread into the 0.4MB L2-resident cnt[].
__global__ __launch_bounds__(256) void convert_kernel(
    const float4* __restrict__ hp, uint2* __restrict__ h8,
    uint4* __restrict__ hbf, const int* __restrict__ dst,
    int* __restrict__ cnt) {
  int t = threadIdx.x, b = blockIdx.x;
  int gid = b * 256 + t;                       // 1.6M threads, 8 floats each
  float4 a = hp[2 * gid], c = hp[2 * gid + 1];
  int lo = __builtin_amdgcn_cvt_pk_fp8_f32(a.x, a.y, 0, false);
  lo = __builtin_amdgcn_cvt_pk_fp8_f32(a.z, a.w, lo, true);
  int hi = __builtin_amdgcn_cvt_pk_fp8_f32(c.x, c.y, 0, false);
  hi = __builtin_amdgcn_cvt_pk_fp8_f32(c.z, c.w, hi, true);
  h8[gid] = make_uint2((unsigned)lo, (unsigned)hi);

  uint4 q;
  q.x = f2bf2(a.x, a.y);
  q.y = f2bf2(a.z, a.w);
  q.z = f2bf2(c.x, c.y);
  q.w = f2bf2(c.z, c.w);
  int m = t >> 4, c8 = t & 15;
  int rt = b & 7, kc = c8 >> 2, quad = c8 & 3;
  hbf[(size_t)(b >> 3) * 2048 + (((rt << 2) + kc) << 6) + (quad << 4) + m] = q;

  atomicAdd(&cnt[dst[gid]], 1);
}

// ---------------- A2. 3-kernel exclusive scan of cnt -> offs, cur -----------
__global__ __launch_bounds__(256) void blocksum_kernel(const int* __restrict__ cnt,
                                                       int* __restrict__ bsum) {
  __shared__ int s[256];
  int t = threadIdx.x;
  s[t] = cnt[blockIdx.x * 256 + t];
  __syncthreads();
  for (int d = 128; d > 0; d >>= 1) {
    if (t < d) s[t] += s[t + d];
    __syncthreads();
  }
  if (t == 0) bsum[blockIdx.x] = s[0];
}

__global__ __launch_bounds__(512) void scanbsum_kernel(const int* __restrict__ bsum,
                                                       int* __restrict__ bsum_ex) {
  __shared__ int s[512];
  int t = threadIdx.x;
  int v = (t < NBUCK) ? bsum[t] : 0;
  s[t] = v;
  __syncthreads();
  for (int d = 1; d < 512; d <<= 1) {
    int x = (t >= d) ? s[t - d] : 0;
    __syncthreads();
    s[t] += x;
    __syncthreads();
  }
  if (t < NBUCK) bsum_ex[t] = s[t] - v;
}

__global__ __launch_bounds__(256) void scanapply_kernel(const int* __restrict__ cnt,
                                                        const int* __restrict__ bsum_ex,
                                                        int* __restrict__ offs,
                                                        int* __restrict__ cur) {
  __shared__ int s[256];
  int t = threadIdx.x;
  int idx = blockIdx.x * 256 + t;
  int v = cnt[idx];
  s[t] = v;
  __syncthreads();
  for (int d = 1; d < 256; d <<= 1) {
    int x = (t >= d) ? s[t - d] : 0;
    __syncthreads();
    s[t] += x;
    __syncthreads();
  }
  int excl = bsum_ex[blockIdx.x] + s[t] - v;
  if (idx < NN) { offs[idx] = excl; cur[idx] = excl; }
  if (idx == NN - 1) offs[NN] = NE;
}

// ---------------- A3. direct atomic scatter -> csr --------------------------
// One atomicAdd-with-return per edge on the per-node cursor; ~16 edges/node
// avg contention. Replaces the whole 2-level bucket sort + ebuf round-trip.
__global__ __launch_bounds__(256) void scatter_kernel(const int* __restrict__ src,
                                                      const int* __restrict__ dst,
                                                      int* __restrict__ cur,
                                                      int* __restrict__ csr) {
  int e = blockIdx.x * 256 + threadIdx.x;      // 1.6M exactly
  int d = dst[e];
  int pos = atomicAdd(&cur[d], 1);
  csr[pos] = src[e];
}

// ---------------- fp8 accumulate helper -------------------------------------
__device__ __forceinline__ void acc16(float* a, uint4 u) {
  f32x2 p;
  p = __builtin_amdgcn_cvt_pk_f32_fp8(u.x, false); a[0] += p.x;  a[1] += p.y;
  p = __builtin_amdgcn_cvt_pk_f32_fp8(u.x, true);  a[2] += p.x;  a[3] += p.y;
  p = __builtin_amdgcn_cvt_pk_f32_fp8(u.y, false); a[4] += p.x;  a[5] += p.y;
  p = __builtin_amdgcn_cvt_pk_f32_fp8(u.y, true);  a[6] += p.x;  a[7] += p.y;
  p = __builtin_amdgcn_cvt_pk_f32_fp8(u.z, false); a[8] += p.x;  a[9] += p.y;
  p = __builtin_amdgcn_cvt_pk_f32_fp8(u.z, true);  a[10] += p.x; a[11] += p.y;
  p = __builtin_amdgcn_cvt_pk_f32_fp8(u.w, false); a[12] += p.x; a[13] += p.y;
  p = __builtin_amdgcn_cvt_pk_f32_fp8(u.w, true);  a[14] += p.x; a[15] += p.y;
}

// ---------------- 4. gather-mean -> bf16 in MFMA-fragment-linear order ------
__global__ __launch_bounds__(256) void gather_frag_kernel(
    const uint4* __restrict__ h8, const int* __restrict__ offs,
    const int* __restrict__ csr, uint4* __restrict__ hfrag) {
  int q = (blockIdx.x * 256 + threadIdx.x) >> 3;   // 0 .. NTILES*128-1 (exact)
  int l = threadIdx.x & 7;                         // 16B chunk within fp8 row
  float a[16];
#pragma unroll
  for (int i = 0; i < 16; i++) a[i] = 0.f;
  float sc = 0.f;
  if (q < NN) {
    int off0 = offs[q], off1 = offs[q + 1];
    int j = off0;
    for (; j + 4 <= off1; j += 4) {
      int s0 = csr[j], s1 = csr[j + 1], s2 = csr[j + 2], s3 = csr[j + 3];
      uint4 u0 = h8[(size_t)s0 * 8 + l];
      uint4 u1 = h8[(size_t)s1 * 8 + l];
      uint4 u2 = h8[(size_t)s2 * 8 + l];
      uint4 u3 = h8[(size_t)s3 * 8 + l];
      acc16(a, u0); acc16(a, u1); acc16(a, u2); acc16(a, u3);
    }
    for (; j < off1; j++) acc16(a, h8[(size_t)csr[j] * 8 + l]);
    int deg = off1 - off0;
    sc = (deg > 0) ? (1.0f / (float)deg) : 0.0f;
  }
  uint4 r0, r1;
  r0.x = f2bf2(a[0] * sc, a[1] * sc);   r0.y = f2bf2(a[2] * sc, a[3] * sc);
  r0.z = f2bf2(a[4] * sc, a[5] * sc);   r0.w = f2bf2(a[6] * sc, a[7] * sc);
  r1.x = f2bf2(a[8] * sc, a[9] * sc);   r1.y = f2bf2(a[10] * sc, a[11] * sc);
  r1.z = f2bf2(a[12] * sc, a[13] * sc); r1.w = f2bf2(a[14] * sc, a[15] * sc);
  int r = q & 127;
  int rt = r >> 4, m = r & 15;
  int kc = l >> 1, quad = (l & 1) << 1;
  int slot = (((rt << 2) + kc) << 6) + (quad << 4) + m;
  uint4* base = hfrag + (size_t)(q >> 7) * 2048;
  base[slot] = r0;
  base[slot + 16] = r1;
}

// ---------------- W staging into fragment-linear LDS ------------------------
__device__ __forceinline__ void stage_w(const float* __restrict__ X,
                                        uint4* buf, int t) {
#pragma unroll
  for (int i = 0; i < 8; i++) {
    int id = t + (i << 8);     // 0..2047
    int r = id >> 4;           // 0..127
    int c8 = id & 15;          // 0..15
    const float4* p = (const float4*)(X + (size_t)r * DD + (c8 << 3));
    float4 v0 = p[0], v1 = p[1];
    uint4 q;
    q.x = f2bf2(v0.x, v0.y);
    q.y = f2bf2(v0.z, v0.w);
    q.z = f2bf2(v1.x, v1.y);
    q.w = f2bf2(v1.z, v1.w);
    int rt = r >> 4, m = r & 15, kc = c8 >> 2, quad = c8 & 3;
    buf[(((rt << 2) + kc) << 6) + (quad << 4) + m] = q;
  }
}

__device__ __forceinline__ void compute_reg(const uint4* a, const uint4* sWb,
                                            f32x4 acc[2][8], int lane) {
#pragma unroll
  for (int kc = 0; kc < 4; kc++) {
    bf16x8 bfr[8];
#pragma unroll
    for (int n = 0; n < 8; n++)
      bfr[n] = *(const bf16x8*)&sWb[(((n << 2) + kc) << 6) + lane];
    bf16x8 a0 = *(const bf16x8*)&a[kc];
    bf16x8 a1 = *(const bf16x8*)&a[4 + kc];
#pragma unroll
    for (int n = 0; n < 8; n++) {
      acc[0][n] = __builtin_amdgcn_mfma_f32_16x16x32_bf16(a0, bfr[n], acc[0][n], 0, 0, 0);
      acc[1][n] = __builtin_amdgcn_mfma_f32_16x16x32_bf16(a1, bfr[n], acc[1][n], 0, 0, 0);
    }
  }
}

// ---------------- 5. out = h@Ws^T + hneigh@Wn^T + b -------------------------
// Both A operands fragment-ordered in HBM -> registers. Single 32KB sW buffer
// staged twice (Wself, then Wneigh) -> 4 blocks/CU (was 2 at 64KB).
__global__ __launch_bounds__(256, 4) void gemm_kernel(
    const uint4* __restrict__ hbf, const uint4* __restrict__ hfrag,
    const float* __restrict__ Wself, const float* __restrict__ Wneigh,
    const float* __restrict__ bias, float* __restrict__ out) {
  __shared__ uint4 sW[2048];   // 32 KB
  int t = threadIdx.x;
  int wv = t >> 6;
  int lane = t & 63;
  int row0 = blockIdx.x * 128;

  const uint4* fb1 = hbf + (size_t)blockIdx.x * 2048;
  const uint4* fb2 = hfrag + (size_t)blockIdx.x * 2048;
  uint4 a1[8], a2[8];
#pragma unroll
  for (int kc = 0; kc < 4; kc++) {
    int s0 = ((((wv * 2 + 0) << 2) + kc) << 6) + lane;
    int s1 = ((((wv * 2 + 1) << 2) + kc) << 6) + lane;
    a1[kc] = fb1[s0]; a1[4 + kc] = fb1[s1];
    a2[kc] = fb2[s0]; a2[4 + kc] = fb2[s1];
  }

  f32x4 acc[2][8];
#pragma unroll
  for (int i = 0; i < 2; i++)
#pragma unroll
    for (int n = 0; n < 8; n++) acc[i][n] = f32x4{0.f, 0.f, 0.f, 0.f};

  stage_w(Wself, sW, t);
  __syncthreads();
  compute_reg(a1, sW, acc, lane);
  __syncthreads();
  stage_w(Wneigh, sW, t);
  __syncthreads();
  compute_reg(a2, sW, acc, lane);

  // epilogue: + bias (C/D layout: col=lane&15, row=(lane>>4)*4+reg)
  int col = lane & 15, rq = lane >> 4;
  float bv[8];
#pragma unroll
  for (int n = 0; n < 8; n++) bv[n] = bias[n * 16 + col];
#pragma unroll
  for (int rt = 0; rt < 2; rt++) {
    int rb = row0 + (wv * 2 + rt) * 16 + rq * 4;
#pragma unroll
    for (int r = 0; r < 4; r++) {
      int row = rb + r;
      if (row < NN) {
        float* op = out + (size_t)row * DD + col;
#pragma unroll
        for (int n = 0; n < 8; n++) op[n * 16] = acc[rt][n][r] + bv[n];
      }
    }
  }
}

extern "C" void kernel_launch(void* const* d_in, const int* in_sizes, int n_in,
                              void* d_out, int out_size, void* d_ws, size_t ws_size,
                              hipStream_t stream) {
  const float* h      = (const float*)d_in[0];
  const int*   src    = (const int*)d_in[1];
  const int*   dst    = (const int*)d_in[2];
  const float* Wself  = (const float*)d_in[3];
  const float* Wneigh = (const float*)d_in[4];
  const float* bias   = (const float*)d_in[5];
  float* out = (float*)d_out;

  // workspace layout (bytes); peak footprint ~71.7 MB
  char* ws = (char*)d_ws;
  unsigned* h8       = (unsigned*)ws;                     // 12,800,000
  unsigned* hbf      = (unsigned*)(ws + 12800000);        // 25,624,576 (782*32768)
  unsigned* hfrag    = (unsigned*)(ws + 38424576);        // 25,624,576
  int*      csr      = (int*)(ws + 64049152);             //  6,400,000
  int*      offs     = (int*)(ws + 70449152);             //    400,016
  int*      cnt      = (int*)(ws + 70849168);             //    400,384
  int*      cur      = (int*)(ws + 71249552);             //    400,384
  int*      bsum     = (int*)(ws + 71649936);             //      1,568
  int*      bsum_ex  = (int*)(ws + 71651504);             //      1,568

  zero_kernel<<<NBUCK, 256, 0, stream>>>(cnt);
  convert_kernel<<<6250, 256, 0, stream>>>((const float4*)h, (uint2*)h8,
                                           (uint4*)hbf, dst, cnt);
  blocksum_kernel<<<NBUCK, 256, 0, stream>>>(cnt, bsum);
  scanbsum_kernel<<<1, 512, 0, stream>>>(bsum, bsum_ex);
  scanapply_kernel<<<NBUCK, 256, 0, stream>>>(cnt, bsum_ex, offs, cur);
  scatter_kernel<<<6250, 256, 0, stream>>>(src, dst, cur, csr);
  gather_frag_kernel<<<(NTILES * 128) / 32, 256, 0, stream>>>(
      (const uint4*)h8, offs, csr, (uint4*)hfrag);
  gemm_kernel<<<NTILES, 256, 0, stream>>>((const uint4*)hbf, (const uint4*)hfrag,
                                          Wself, Wneigh, bias, out);
}

// Round 6
// 239.225 us; speedup vs baseline: 1.5260x; 1.5260x over previous
//
#include <hip/hip_runtime.h>
#include <stdint.h>

#define NN 100000
#define NE 1600000
#define DD 128
#define NTILES ((NN + 127) / 128)   // 782
#define NB 512                      // phase-A blocks
#define CHUNK (NE / NB)             // 3125
#define NBUCK ((NN + 255) / 256)    // 391 coarse buckets (dst>>8)
#define MAXBE 6144                  // max edges/bucket (avg 4092, sigma 64)

typedef __bf16 bf16x8 __attribute__((ext_vector_type(8)));
typedef float f32x4 __attribute__((ext_vector_type(4)));
typedef float f32x2 __attribute__((ext_vector_type(2)));

// round-to-nearest-even fp32 -> bf16, two at a time, packed into a uint
__device__ __forceinline__ unsigned int f2bf2(float a, float b) {
  union { float f; unsigned u; } x, y;
  x.f = a; y.f = b;
  unsigned ua = x.u + (0x7FFFu + ((x.u >> 16) & 1u));
  unsigned ub = y.u + (0x7FFFu + ((y.u >> 16) & 1u));
  return (ua >> 16) | (ub & 0xFFFF0000u);
}

// ---------------- 00. zero ghist + gcur (workspace arrives poisoned) --------
__global__ __launch_bounds__(256) void zero_kernel(int* __restrict__ p) {
  int t = blockIdx.x * 256 + threadIdx.x;
  if (t < 2 * NBUCK) p[t] = 0;
}

// ---------------- 0+A1. h -> h8 (fp8) + hbf (bf16 fragment order) + hist ----
// Block b covers rows b*16 .. b*16+15 (6250*16 = 100,000 exactly).
// Blocks < NB additionally histogram their 3125-edge chunk into the global
// 391-entry bucket histogram (LDS-aggregated, then ~391 global atomics).
__global__ __launch_bounds__(256) void convert_kernel(
    const float4* __restrict__ hp, uint2* __restrict__ h8,
    uint4* __restrict__ hbf, const int* __restrict__ dst,
    int* __restrict__ ghist) {
  __shared__ int lh[NBUCK];
  int t = threadIdx.x, b = blockIdx.x;
  int gid = b * 256 + t;                       // 1.6M threads, 8 floats each
  float4 a = hp[2 * gid], c = hp[2 * gid + 1];
  int lo = __builtin_amdgcn_cvt_pk_fp8_f32(a.x, a.y, 0, false);
  lo = __builtin_amdgcn_cvt_pk_fp8_f32(a.z, a.w, lo, true);
  int hi = __builtin_amdgcn_cvt_pk_fp8_f32(c.x, c.y, 0, false);
  hi = __builtin_amdgcn_cvt_pk_fp8_f32(c.z, c.w, hi, true);
  h8[gid] = make_uint2((unsigned)lo, (unsigned)hi);

  uint4 q;
  q.x = f2bf2(a.x, a.y);
  q.y = f2bf2(a.z, a.w);
  q.z = f2bf2(c.x, c.y);
  q.w = f2bf2(c.z, c.w);
  int m = t >> 4, c8 = t & 15;
  int rt = b & 7, kc = c8 >> 2, quad = c8 & 3;
  hbf[(size_t)(b >> 3) * 2048 + (((rt << 2) + kc) << 6) + (quad << 4) + m] = q;

  if (b < NB) {   // block-uniform branch: __syncthreads inside is safe
    for (int i = t; i < NBUCK; i += 256) lh[i] = 0;
    __syncthreads();
    int e0 = b * CHUNK;
    for (int e = e0 + t; e < e0 + CHUNK; e += 256)
      atomicAdd(&lh[dst[e] >> 8], 1);
    __syncthreads();
    for (int i = t; i < NBUCK; i += 256)
      if (lh[i]) atomicAdd(&ghist[i], lh[i]);
  }
}

// ---------------- A3. coarse scatter: internal scan + atomic reservation ----
// Each block: local bucket hist of its chunk, dual LDS scan (local counts for
// LDS layout + global hist for bucket bases), one atomicAdd per non-empty
// bucket to reserve a contiguous range, LDS-stage, ordered burst writeback.
__global__ __launch_bounds__(256) void coarse_scatter_kernel(
    const int* __restrict__ src, const int* __restrict__ dst,
    const int* __restrict__ ghist, int* __restrict__ gcur,
    unsigned* __restrict__ ebuf) {
  __shared__ int lhp[512];    // local hist -> inclusive scan
  __shared__ int gbp[512];    // global hist -> inclusive scan
  __shared__ int lbase[NBUCK];
  __shared__ int lcur[NBUCK];
  __shared__ int gstart[NBUCK];
  __shared__ unsigned sdata[CHUNK];
  __shared__ int sgpos[CHUNK];
  int t = threadIdx.x, b = blockIdx.x;
  lhp[t] = 0;
  lhp[t + 256] = 0;
  gbp[t] = (t < NBUCK) ? ghist[t] : 0;
  gbp[t + 256] = (t + 256 < NBUCK) ? ghist[t + 256] : 0;
  __syncthreads();
  int e0 = b * CHUNK;
  for (int e = e0 + t; e < e0 + CHUNK; e += 256)
    atomicAdd(&lhp[dst[e] >> 8], 1);
  __syncthreads();
  int c0 = lhp[t], c1 = lhp[t + 256];
  int g0 = gbp[t], g1 = gbp[t + 256];
  for (int d = 1; d < 512; d <<= 1) {
    int x0 = (t >= d) ? lhp[t - d] : 0;
    int x1 = ((t + 256) >= d) ? lhp[t + 256 - d] : 0;
    int y0 = (t >= d) ? gbp[t - d] : 0;
    int y1 = ((t + 256) >= d) ? gbp[t + 256 - d] : 0;
    __syncthreads();
    lhp[t] += x0; lhp[t + 256] += x1;
    gbp[t] += y0; gbp[t + 256] += y1;
    __syncthreads();
  }
  if (t < NBUCK) {
    lbase[t] = lhp[t] - c0;
    lcur[t] = 0;
    int resv = c0 ? atomicAdd(&gcur[t], c0) : 0;
    gstart[t] = (gbp[t] - g0) + resv;          // bucket base (exclusive) + slice
  }
  int i2 = t + 256;
  if (i2 < NBUCK) {
    lbase[i2] = lhp[i2] - c1;
    lcur[i2] = 0;
    int resv = c1 ? atomicAdd(&gcur[i2], c1) : 0;
    gstart[i2] = (gbp[i2] - g1) + resv;
  }
  __syncthreads();
  for (int e = e0 + t; e < e0 + CHUNK; e += 256) {
    int d = dst[e], s = src[e];
    int bk = d >> 8;
    int slot = atomicAdd(&lcur[bk], 1);
    int lp = lbase[bk] + slot;
    sdata[lp] = ((unsigned)(d & 255) << 24) | (unsigned)s;
    sgpos[lp] = gstart[bk] + slot;
  }
  __syncthreads();
  for (int j = t; j < CHUNK; j += 256) ebuf[sgpos[j]] = sdata[j];
}

// ---------------- fp8 accumulate helper -------------------------------------
__device__ __forceinline__ void acc16(float* a, uint4 u) {
  f32x2 p;
  p = __builtin_amdgcn_cvt_pk_f32_fp8(u.x, false); a[0] += p.x;  a[1] += p.y;
  p = __builtin_amdgcn_cvt_pk_f32_fp8(u.x, true);  a[2] += p.x;  a[3] += p.y;
  p = __builtin_amdgcn_cvt_pk_f32_fp8(u.y, false); a[4] += p.x;  a[5] += p.y;
  p = __builtin_amdgcn_cvt_pk_f32_fp8(u.y, true);  a[6] += p.x;  a[7] += p.y;
  p = __builtin_amdgcn_cvt_pk_f32_fp8(u.z, false); a[8] += p.x;  a[9] += p.y;
  p = __builtin_amdgcn_cvt_pk_f32_fp8(u.z, true);  a[10] += p.x; a[11] += p.y;
  p = __builtin_amdgcn_cvt_pk_f32_fp8(u.w, false); a[12] += p.x; a[13] += p.y;
  p = __builtin_amdgcn_cvt_pk_f32_fp8(u.w, true);  a[14] += p.x; a[15] += p.y;
}

// ---------------- B+4. fused: fine sort (LDS) + gather-mean -> hfrag --------
// 2 blocks per bucket; block = GEMM tile (bid = 2*bucket + half). Each block
// sorts its bucket's edges into LDS (hist/scan/scatter, exactly fine_sort's
// logic but LDS-resident -> no csr HBM round-trip), then 8-lane groups
// accumulate fp8 rows per node and write bf16 fragments for their 128 rows.
__global__ __launch_bounds__(256) void gather_bucket_kernel(
    const unsigned* __restrict__ ebuf, const int* __restrict__ ghist,
    const uint4* __restrict__ h8, uint4* __restrict__ hfrag) {
  __shared__ int gbp[512];
  __shared__ int hist[256], st[256], cur[256];
  __shared__ int ssort[MAXBE];
  int t = threadIdx.x;
  int bid = blockIdx.x;
  int g = bid >> 1, p = bid & 1;
  gbp[t] = (t < NBUCK) ? ghist[t] : 0;
  gbp[t + 256] = (t + 256 < NBUCK) ? ghist[t + 256] : 0;
  hist[t] = 0;
  __syncthreads();
  for (int d = 1; d < 512; d <<= 1) {
    int y0 = (t >= d) ? gbp[t - d] : 0;
    int y1 = ((t + 256) >= d) ? gbp[t + 256 - d] : 0;
    __syncthreads();
    gbp[t] += y0; gbp[t + 256] += y1;
    __syncthreads();
  }
  int end = gbp[g];                 // inclusive scan at g
  int base = end - ghist[g];        // exclusive
  // pass A: node histogram (ebuf segment is L2-hot, ~16 KB)
  for (int j = base + t; j < end; j += 256)
    atomicAdd(&hist[ebuf[j] >> 24], 1);
  __syncthreads();
  int deg = hist[t];
  st[t] = deg;
  __syncthreads();
  for (int d = 1; d < 256; d <<= 1) {
    int x = (t >= d) ? st[t - d] : 0;
    __syncthreads();
    st[t] += x;
    __syncthreads();
  }
  int start = st[t] - deg;          // exclusive scan
  __syncthreads();
  st[t] = start;
  cur[t] = start;
  __syncthreads();
  // pass B: sort into LDS
  for (int j = base + t; j < end; j += 256) {
    unsigned e = ebuf[j];
    int pos = atomicAdd(&cur[e >> 24], 1);
    ssort[pos] = (int)(e & 0x00FFFFFFu);
  }
  __syncthreads();
  // gather: 32 groups of 8 lanes; each group handles 4 of this half's 128 rows
  int grp = t >> 3, l = t & 7;
#pragma unroll 1
  for (int k = 0; k < 4; k++) {
    int r = grp * 4 + k;            // row within this tile (0..127)
    int ln = p * 128 + r;           // local node within bucket
    int j = st[ln];
    int jend = j + hist[ln];
    float a[16];
#pragma unroll
    for (int i = 0; i < 16; i++) a[i] = 0.f;
    for (; j + 4 <= jend; j += 4) {
      int s0 = ssort[j], s1 = ssort[j + 1], s2 = ssort[j + 2], s3 = ssort[j + 3];
      uint4 u0 = h8[(size_t)s0 * 8 + l];
      uint4 u1 = h8[(size_t)s1 * 8 + l];
      uint4 u2 = h8[(size_t)s2 * 8 + l];
      uint4 u3 = h8[(size_t)s3 * 8 + l];
      acc16(a, u0); acc16(a, u1); acc16(a, u2); acc16(a, u3);
    }
    for (; j < jend; j++) acc16(a, h8[(size_t)ssort[j] * 8 + l]);
    int dg = hist[ln];
    float sc = (dg > 0) ? (1.0f / (float)dg) : 0.0f;
    uint4 r0, r1;
    r0.x = f2bf2(a[0] * sc, a[1] * sc);   r0.y = f2bf2(a[2] * sc, a[3] * sc);
    r0.z = f2bf2(a[4] * sc, a[5] * sc);   r0.w = f2bf2(a[6] * sc, a[7] * sc);
    r1.x = f2bf2(a[8] * sc, a[9] * sc);   r1.y = f2bf2(a[10] * sc, a[11] * sc);
    r1.z = f2bf2(a[12] * sc, a[13] * sc); r1.w = f2bf2(a[14] * sc, a[15] * sc);
    int rt = r >> 4, m = r & 15;
    int kc = l >> 1, quad = (l & 1) << 1;
    int slot = (((rt << 2) + kc) << 6) + (quad << 4) + m;
    uint4* bp = hfrag + (size_t)bid * 2048;
    bp[slot] = r0;
    bp[slot + 16] = r1;
  }
}

// ---------------- W staging into fragment-linear LDS ------------------------
__device__ __forceinline__ void stage_w(const float* __restrict__ X,
                                        uint4* buf, int t) {
#pragma unroll
  for (int i = 0; i < 8; i++) {
    int id = t + (i << 8);     // 0..2047
    int r = id >> 4;           // 0..127
    int c8 = id & 15;          // 0..15
    const float4* p = (const float4*)(X + (size_t)r * DD + (c8 << 3));
    float4 v0 = p[0], v1 = p[1];
    uint4 q;
    q.x = f2bf2(v0.x, v0.y);
    q.y = f2bf2(v0.z, v0.w);
    q.z = f2bf2(v1.x, v1.y);
    q.w = f2bf2(v1.z, v1.w);
    int rt = r >> 4, m = r & 15, kc = c8 >> 2, quad = c8 & 3;
    buf[(((rt << 2) + kc) << 6) + (quad << 4) + m] = q;
  }
}

__device__ __forceinline__ void compute_reg(const uint4* a, const uint4* sWb,
                                            f32x4 acc[2][8], int lane) {
#pragma unroll
  for (int kc = 0; kc < 4; kc++) {
    bf16x8 bfr[8];
#pragma unroll
    for (int n = 0; n < 8; n++)
      bfr[n] = *(const bf16x8*)&sWb[(((n << 2) + kc) << 6) + lane];
    bf16x8 a0 = *(const bf16x8*)&a[kc];
    bf16x8 a1 = *(const bf16x8*)&a[4 + kc];
#pragma unroll
    for (int n = 0; n < 8; n++) {
      acc[0][n] = __builtin_amdgcn_mfma_f32_16x16x32_bf16(a0, bfr[n], acc[0][n], 0, 0, 0);
      acc[1][n] = __builtin_amdgcn_mfma_f32_16x16x32_bf16(a1, bfr[n], acc[1][n], 0, 0, 0);
    }
  }
}

// ---------------- 5. out = h@Ws^T + hneigh@Wn^T + b -------------------------
// Both A operands fragment-ordered in HBM -> registers. Single 32KB sW buffer
// staged twice (Wself, then Wneigh) -> 4 blocks/CU.
__global__ __launch_bounds__(256, 4) void gemm_kernel(
    const uint4* __restrict__ hbf, const uint4* __restrict__ hfrag,
    const float* __restrict__ Wself, const float* __restrict__ Wneigh,
    const float* __restrict__ bias, float* __restrict__ out) {
  __shared__ uint4 sW[2048];   // 32 KB
  int t = threadIdx.x;
  int wv = t >> 6;
  int lane = t & 63;
  int row0 = blockIdx.x * 128;

  const uint4* fb1 = hbf + (size_t)blockIdx.x * 2048;
  const uint4* fb2 = hfrag + (size_t)blockIdx.x * 2048;
  uint4 a1[8], a2[8];
#pragma unroll
  for (int kc = 0; kc < 4; kc++) {
    int s0 = ((((wv * 2 + 0) << 2) + kc) << 6) + lane;
    int s1 = ((((wv * 2 + 1) << 2) + kc) << 6) + lane;
    a1[kc] = fb1[s0]; a1[4 + kc] = fb1[s1];
    a2[kc] = fb2[s0]; a2[4 + kc] = fb2[s1];
  }

  f32x4 acc[2][8];
#pragma unroll
  for (int i = 0; i < 2; i++)
#pragma unroll
    for (int n = 0; n < 8; n++) acc[i][n] = f32x4{0.f, 0.f, 0.f, 0.f};

  stage_w(Wself, sW, t);
  __syncthreads();
  compute_reg(a1, sW, acc, lane);
  __syncthreads();
  stage_w(Wneigh, sW, t);
  __syncthreads();
  compute_reg(a2, sW, acc, lane);

  // epilogue: + bias (C/D layout: col=lane&15, row=(lane>>4)*4+reg)
  int col = lane & 15, rq = lane >> 4;
  float bv[8];
#pragma unroll
  for (int n = 0; n < 8; n++) bv[n] = bias[n * 16 + col];
#pragma unroll
  for (int rt = 0; rt < 2; rt++) {
    int rb = row0 + (wv * 2 + rt) * 16 + rq * 4;
#pragma unroll
    for (int r = 0; r < 4; r++) {
      int row = rb + r;
      if (row < NN) {
        float* op = out + (size_t)row * DD + col;
#pragma unroll
        for (int n = 0; n < 8; n++) op[n * 16] = acc[rt][n][r] + bv[n];
      }
    }
  }
}

extern "C" void kernel_launch(void* const* d_in, const int* in_sizes, int n_in,
                              void* d_out, int out_size, void* d_ws, size_t ws_size,
                              hipStream_t stream) {
  const float* h      = (const float*)d_in[0];
  const int*   src    = (const int*)d_in[1];
  const int*   dst    = (const int*)d_in[2];
  const float* Wself  = (const float*)d_in[3];
  const float* Wneigh = (const float*)d_in[4];
  const float* bias   = (const float*)d_in[5];
  float* out = (float*)d_out;

  // workspace layout (bytes); peak footprint ~70.7 MB
  char* ws = (char*)d_ws;
  unsigned* h8       = (unsigned*)ws;                     // 12,800,000
  unsigned* hbf      = (unsigned*)(ws + 12800000);        // 25,624,576 (782*32768)
  unsigned* hfrag    = (unsigned*)(ws + 38424576);        // 25,624,576
  unsigned* ebuf     = (unsigned*)(ws + 64049152);        //  6,400,000
  int*      ghist    = (int*)(ws + 70449152);             //      1,564
  int*      gcur     = (int*)(ws + 70450716);             //      1,564

  zero_kernel<<<4, 256, 0, stream>>>(ghist);              // zeros ghist+gcur
  convert_kernel<<<6250, 256, 0, stream>>>((const float4*)h, (uint2*)h8,
                                           (uint4*)hbf, dst, ghist);
  coarse_scatter_kernel<<<NB, 256, 0, stream>>>(src, dst, ghist, gcur, ebuf);
  gather_bucket_kernel<<<NTILES, 256, 0, stream>>>(ebuf, ghist,
                                                   (const uint4*)h8, (uint4*)hfrag);
  gemm_kernel<<<NTILES, 256, 0, stream>>>((const uint4*)hbf, (const uint4*)hfrag,
                                          Wself, Wneigh, bias, out);
}

// Round 7
// 221.641 us; speedup vs baseline: 1.6471x; 1.0793x over previous
//
#include <hip/hip_runtime.h>
#include <stdint.h>

#define NN 100000
#define NE 1600000
#define DD 128
#define NTILES ((NN + 127) / 128)   // 782
#define NB 512                      // scatter blocks
#define CHUNK (NE / NB)             // 3125
#define NBUCK ((NN + 255) / 256)    // 391 coarse buckets (dst>>8)
#define BCAP 4608                   // bucket capacity (mean 4096, +8 sigma)
#define QCAP 1536                   // quarter capacity (mean 1024, +16 sigma)

typedef __bf16 bf16x8 __attribute__((ext_vector_type(8)));
typedef float f32x4 __attribute__((ext_vector_type(4)));
typedef float f32x2 __attribute__((ext_vector_type(2)));

// round-to-nearest-even fp32 -> bf16, two at a time, packed into a uint
__device__ __forceinline__ unsigned int f2bf2(float a, float b) {
  union { float f; unsigned u; } x, y;
  x.f = a; y.f = b;
  unsigned ua = x.u + (0x7FFFu + ((x.u >> 16) & 1u));
  unsigned ub = y.u + (0x7FFFu + ((y.u >> 16) & 1u));
  return (ua >> 16) | (ub & 0xFFFF0000u);
}

// ---------------- 00. zero bucket cursors (workspace arrives poisoned) ------
__global__ __launch_bounds__(256) void zero_kernel(int* __restrict__ gcur) {
  int t = blockIdx.x * 256 + threadIdx.x;
  if (t < NBUCK) gcur[t] = 0;
}

// ---------------- 0. h -> h8 (fp8 e4m3) + hbf (bf16 fragment order) ---------
// Block b covers rows b*16 .. b*16+15 (6250*16 = 100,000 exactly). Pure BW.
__global__ __launch_bounds__(256) void convert_kernel(
    const float4* __restrict__ hp, uint2* __restrict__ h8,
    uint4* __restrict__ hbf) {
  int t = threadIdx.x, b = blockIdx.x;
  int gid = b * 256 + t;                       // 1.6M threads, 8 floats each
  float4 a = hp[2 * gid], c = hp[2 * gid + 1];
  int lo = __builtin_amdgcn_cvt_pk_fp8_f32(a.x, a.y, 0, false);
  lo = __builtin_amdgcn_cvt_pk_fp8_f32(a.z, a.w, lo, true);
  int hi = __builtin_amdgcn_cvt_pk_fp8_f32(c.x, c.y, 0, false);
  hi = __builtin_amdgcn_cvt_pk_fp8_f32(c.z, c.w, hi, true);
  h8[gid] = make_uint2((unsigned)lo, (unsigned)hi);

  uint4 q;
  q.x = f2bf2(a.x, a.y);
  q.y = f2bf2(a.z, a.w);
  q.z = f2bf2(c.x, c.y);
  q.w = f2bf2(c.z, c.w);
  int m = t >> 4, c8 = t & 15;
  int rt = b & 7, kc = c8 >> 2, quad = c8 & 3;
  hbf[(size_t)(b >> 3) * 2048 + (((rt << 2) + kc) << 6) + (quad << 4) + m] = q;
}

// ---------------- A. coarse scatter into fixed-capacity buckets -------------
// Local bucket hist + LDS scan; one atomicAdd per non-empty bucket reserves a
// contiguous slice at bk*BCAP + cursor; LDS-stage then ordered burst write.
__global__ __launch_bounds__(256) void coarse_scatter_kernel(
    const int* __restrict__ src, const int* __restrict__ dst,
    int* __restrict__ gcur, unsigned* __restrict__ ebuf) {
  __shared__ int lhp[512];
  __shared__ int lbase[NBUCK];
  __shared__ int lcur[NBUCK];
  __shared__ int gstart[NBUCK];
  __shared__ unsigned sdata[CHUNK];
  __shared__ int sgpos[CHUNK];
  int t = threadIdx.x, b = blockIdx.x;
  lhp[t] = 0;
  lhp[t + 256] = 0;
  __syncthreads();
  int e0 = b * CHUNK;
  for (int e = e0 + t; e < e0 + CHUNK; e += 256)
    atomicAdd(&lhp[dst[e] >> 8], 1);
  __syncthreads();
  int c0 = lhp[t], c1 = lhp[t + 256];
  for (int d = 1; d < 512; d <<= 1) {
    int x0 = (t >= d) ? lhp[t - d] : 0;
    int x1 = ((t + 256) >= d) ? lhp[t + 256 - d] : 0;
    __syncthreads();
    lhp[t] += x0;
    lhp[t + 256] += x1;
    __syncthreads();
  }
  if (t < NBUCK) {
    lbase[t] = lhp[t] - c0;
    lcur[t] = 0;
    gstart[t] = t * BCAP + (c0 ? atomicAdd(&gcur[t], c0) : 0);
  }
  int i2 = t + 256;
  if (i2 < NBUCK) {
    lbase[i2] = lhp[i2] - c1;
    lcur[i2] = 0;
    gstart[i2] = i2 * BCAP + (c1 ? atomicAdd(&gcur[i2], c1) : 0);
  }
  __syncthreads();
  for (int e = e0 + t; e < e0 + CHUNK; e += 256) {
    int d = dst[e], s = src[e];
    int bk = d >> 8;
    int slot = atomicAdd(&lcur[bk], 1);
    int lp = lbase[bk] + slot;
    sdata[lp] = ((unsigned)(d & 255) << 24) | (unsigned)s;
    sgpos[lp] = gstart[bk] + slot;
  }
  __syncthreads();
  for (int j = t; j < CHUNK; j += 256) ebuf[sgpos[j]] = sdata[j];
}

// ---------------- fp8 accumulate helper -------------------------------------
__device__ __forceinline__ void acc16(float* a, uint4 u) {
  f32x2 p;
  p = __builtin_amdgcn_cvt_pk_f32_fp8(u.x, false); a[0] += p.x;  a[1] += p.y;
  p = __builtin_amdgcn_cvt_pk_f32_fp8(u.x, true);  a[2] += p.x;  a[3] += p.y;
  p = __builtin_amdgcn_cvt_pk_f32_fp8(u.y, false); a[4] += p.x;  a[5] += p.y;
  p = __builtin_amdgcn_cvt_pk_f32_fp8(u.y, true);  a[6] += p.x;  a[7] += p.y;
  p = __builtin_amdgcn_cvt_pk_f32_fp8(u.z, false); a[8] += p.x;  a[9] += p.y;
  p = __builtin_amdgcn_cvt_pk_f32_fp8(u.z, true);  a[10] += p.x; a[11] += p.y;
  p = __builtin_amdgcn_cvt_pk_f32_fp8(u.w, false); a[12] += p.x; a[13] += p.y;
  p = __builtin_amdgcn_cvt_pk_f32_fp8(u.w, true);  a[14] += p.x; a[15] += p.y;
}

// ---------------- B+4. quarter-bucket: LDS sort + pipelined gather ----------
// 4 blocks per bucket, 64 nodes each (grid 1564 -> ~6 blocks/CU). Each block
// hists/sorts ONLY its own 64 nodes' edges into LDS (7 KB), then 8-lane
// groups gather h8 rows with a depth-2 software pipeline and write bf16
// fragments. Out-of-range nodes (>= NN) have no edges -> zero fragments.
__global__ __launch_bounds__(256, 4) void gather_bucket_kernel(
    const unsigned* __restrict__ ebuf, const int* __restrict__ gcur,
    const uint4* __restrict__ h8, uint4* __restrict__ hfrag) {
  __shared__ int hist[64], st[64], cur[64];
  __shared__ int ssort[QCAP];
  int t = threadIdx.x, bid = blockIdx.x;
  int g = bid >> 2, qt = bid & 3;
  int base = g * BCAP;
  int cnt = gcur[g];
  int lo = qt * 64;
  if (t < 64) hist[t] = 0;
  __syncthreads();
  // pass A: histogram own quarter's nodes (ebuf segment is L2-hot)
  for (int j = t; j < cnt; j += 256) {
    int dn = (int)(ebuf[base + j] >> 24) - lo;
    if ((unsigned)dn < 64u) atomicAdd(&hist[dn], 1);
  }
  __syncthreads();
  if (t < 64) st[t] = hist[t];
  __syncthreads();
  for (int d = 1; d < 64; d <<= 1) {
    int x = (t < 64 && t >= d) ? st[t - d] : 0;
    __syncthreads();
    if (t < 64) st[t] += x;
    __syncthreads();
  }
  if (t < 64) {
    int s = st[t] - hist[t];
    st[t] = s;
    cur[t] = s;
  }
  __syncthreads();
  // pass B: sort own edges into LDS
  for (int j = t; j < cnt; j += 256) {
    unsigned e = ebuf[base + j];
    int dn = (int)(e >> 24) - lo;
    if ((unsigned)dn < 64u) {
      int pos = atomicAdd(&cur[dn], 1);
      if (pos < QCAP) ssort[pos] = (int)(e & 0x00FFFFFFu);
    }
  }
  __syncthreads();
  // gather: 32 groups of 8 lanes; 2 rounds -> 64 nodes
  int grp = t >> 3, l = t & 7;
  uint4* bp = hfrag + (size_t)(bid >> 1) * 2048;
#pragma unroll 1
  for (int rnd = 0; rnd < 2; rnd++) {
    int li = rnd * 32 + grp;          // local node 0..63
    int deg = hist[li];
    int j0 = st[li];
    float a[16];
#pragma unroll
    for (int i = 0; i < 16; i++) a[i] = 0.f;
    int jmax = deg & ~3;
    if (jmax > 0) {
      int s0 = ssort[j0], s1 = ssort[j0 + 1], s2 = ssort[j0 + 2], s3 = ssort[j0 + 3];
      uint4 u0 = h8[(size_t)s0 * 8 + l];
      uint4 u1 = h8[(size_t)s1 * 8 + l];
      uint4 u2 = h8[(size_t)s2 * 8 + l];
      uint4 u3 = h8[(size_t)s3 * 8 + l];
      for (int j4 = 4; j4 < jmax; j4 += 4) {
        int t0 = ssort[j0 + j4], t1 = ssort[j0 + j4 + 1];
        int t2 = ssort[j0 + j4 + 2], t3 = ssort[j0 + j4 + 3];
        uint4 v0 = h8[(size_t)t0 * 8 + l];
        uint4 v1 = h8[(size_t)t1 * 8 + l];
        uint4 v2 = h8[(size_t)t2 * 8 + l];
        uint4 v3 = h8[(size_t)t3 * 8 + l];
        acc16(a, u0); acc16(a, u1); acc16(a, u2); acc16(a, u3);
        u0 = v0; u1 = v1; u2 = v2; u3 = v3;
      }
      acc16(a, u0); acc16(a, u1); acc16(a, u2); acc16(a, u3);
    }
    for (int j2 = jmax; j2 < deg; j2++) acc16(a, h8[(size_t)ssort[j0 + j2] * 8 + l]);
    float sc = (deg > 0) ? (1.0f / (float)deg) : 0.0f;
    uint4 r0, r1;
    r0.x = f2bf2(a[0] * sc, a[1] * sc);   r0.y = f2bf2(a[2] * sc, a[3] * sc);
    r0.z = f2bf2(a[4] * sc, a[5] * sc);   r0.w = f2bf2(a[6] * sc, a[7] * sc);
    r1.x = f2bf2(a[8] * sc, a[9] * sc);   r1.y = f2bf2(a[10] * sc, a[11] * sc);
    r1.z = f2bf2(a[12] * sc, a[13] * sc); r1.w = f2bf2(a[14] * sc, a[15] * sc);
    int r = ((qt & 1) << 6) + li;     // row within 128-row tile
    int rt = r >> 4, m = r & 15;
    int kc = l >> 1, quad = (l & 1) << 1;
    int slot = (((rt << 2) + kc) << 6) + (quad << 4) + m;
    bp[slot] = r0;
    bp[slot + 16] = r1;
  }
}

// ---------------- W staging into fragment-linear LDS ------------------------
__device__ __forceinline__ void stage_w(const float* __restrict__ X,
                                        uint4* buf, int t) {
#pragma unroll
  for (int i = 0; i < 8; i++) {
    int id = t + (i << 8);     // 0..2047
    int r = id >> 4;           // 0..127
    int c8 = id & 15;          // 0..15
    const float4* p = (const float4*)(X + (size_t)r * DD + (c8 << 3));
    float4 v0 = p[0], v1 = p[1];
    uint4 q;
    q.x = f2bf2(v0.x, v0.y);
    q.y = f2bf2(v0.z, v0.w);
    q.z = f2bf2(v1.x, v1.y);
    q.w = f2bf2(v1.z, v1.w);
    int rt = r >> 4, m = r & 15, kc = c8 >> 2, quad = c8 & 3;
    buf[(((rt << 2) + kc) << 6) + (quad << 4) + m] = q;
  }
}

__device__ __forceinline__ void compute_reg(const uint4* a, const uint4* sWb,
                                            f32x4 acc[2][8], int lane) {
#pragma unroll
  for (int kc = 0; kc < 4; kc++) {
    bf16x8 bfr[8];
#pragma unroll
    for (int n = 0; n < 8; n++)
      bfr[n] = *(const bf16x8*)&sWb[(((n << 2) + kc) << 6) + lane];
    bf16x8 a0 = *(const bf16x8*)&a[kc];
    bf16x8 a1 = *(const bf16x8*)&a[4 + kc];
#pragma unroll
    for (int n = 0; n < 8; n++) {
      acc[0][n] = __builtin_amdgcn_mfma_f32_16x16x32_bf16(a0, bfr[n], acc[0][n], 0, 0, 0);
      acc[1][n] = __builtin_amdgcn_mfma_f32_16x16x32_bf16(a1, bfr[n], acc[1][n], 0, 0, 0);
    }
  }
}

// ---------------- 5. out = h@Ws^T + hneigh@Wn^T + b -------------------------
// Both A operands fragment-ordered in HBM -> registers. Single 32KB sW buffer
// staged twice (Wself, then Wneigh) -> 4 blocks/CU.
__global__ __launch_bounds__(256, 4) void gemm_kernel(
    const uint4* __restrict__ hbf, const uint4* __restrict__ hfrag,
    const float* __restrict__ Wself, const float* __restrict__ Wneigh,
    const float* __restrict__ bias, float* __restrict__ out) {
  __shared__ uint4 sW[2048];   // 32 KB
  int t = threadIdx.x;
  int wv = t >> 6;
  int lane = t & 63;
  int row0 = blockIdx.x * 128;

  const uint4* fb1 = hbf + (size_t)blockIdx.x * 2048;
  const uint4* fb2 = hfrag + (size_t)blockIdx.x * 2048;
  uint4 a1[8], a2[8];
#pragma unroll
  for (int kc = 0; kc < 4; kc++) {
    int s0 = ((((wv * 2 + 0) << 2) + kc) << 6) + lane;
    int s1 = ((((wv * 2 + 1) << 2) + kc) << 6) + lane;
    a1[kc] = fb1[s0]; a1[4 + kc] = fb1[s1];
    a2[kc] = fb2[s0]; a2[4 + kc] = fb2[s1];
  }

  f32x4 acc[2][8];
#pragma unroll
  for (int i = 0; i < 2; i++)
#pragma unroll
    for (int n = 0; n < 8; n++) acc[i][n] = f32x4{0.f, 0.f, 0.f, 0.f};

  stage_w(Wself, sW, t);
  __syncthreads();
  compute_reg(a1, sW, acc, lane);
  __syncthreads();
  stage_w(Wneigh, sW, t);
  __syncthreads();
  compute_reg(a2, sW, acc, lane);

  // epilogue: + bias (C/D layout: col=lane&15, row=(lane>>4)*4+reg)
  int col = lane & 15, rq = lane >> 4;
  float bv[8];
#pragma unroll
  for (int n = 0; n < 8; n++) bv[n] = bias[n * 16 + col];
#pragma unroll
  for (int rt = 0; rt < 2; rt++) {
    int rb = row0 + (wv * 2 + rt) * 16 + rq * 4;
#pragma unroll
    for (int r = 0; r < 4; r++) {
      int row = rb + r;
      if (row < NN) {
        float* op = out + (size_t)row * DD + col;
#pragma unroll
        for (int n = 0; n < 8; n++) op[n * 16] = acc[rt][n][r] + bv[n];
      }
    }
  }
}

extern "C" void kernel_launch(void* const* d_in, const int* in_sizes, int n_in,
                              void* d_out, int out_size, void* d_ws, size_t ws_size,
                              hipStream_t stream) {
  const float* h      = (const float*)d_in[0];
  const int*   src    = (const int*)d_in[1];
  const int*   dst    = (const int*)d_in[2];
  const float* Wself  = (const float*)d_in[3];
  const float* Wneigh = (const float*)d_in[4];
  const float* bias   = (const float*)d_in[5];
  float* out = (float*)d_out;

  // workspace layout (bytes); peak footprint ~71.3 MB
  char* ws = (char*)d_ws;
  unsigned* h8       = (unsigned*)ws;                     // 12,800,000
  unsigned* hbf      = (unsigned*)(ws + 12800000);        // 25,624,576 (782*32768)
  unsigned* hfrag    = (unsigned*)(ws + 38424576);        // 25,624,576
  unsigned* ebuf     = (unsigned*)(ws + 64049152);        //  7,206,912 (391*4608*4)
  int*      gcur     = (int*)(ws + 71256064);             //      1,564

  zero_kernel<<<2, 256, 0, stream>>>(gcur);
  convert_kernel<<<6250, 256, 0, stream>>>((const float4*)h, (uint2*)h8,
                                           (uint4*)hbf);
  coarse_scatter_kernel<<<NB, 256, 0, stream>>>(src, dst, gcur, ebuf);
  gather_bucket_kernel<<<NBUCK * 4, 256, 0, stream>>>(ebuf, gcur,
                                                      (const uint4*)h8,
                                                      (uint4*)hfrag);
  gemm_kernel<<<NTILES, 256, 0, stream>>>((const uint4*)hbf, (const uint4*)hfrag,
                                          Wself, Wneigh, bias, out);
}

// Round 8
// 203.282 us; speedup vs baseline: 1.7958x; 1.0903x over previous
//
#include <hip/hip_runtime.h>
#include <stdint.h>

#define NN 100000
#define NE 1600000
#define DD 128
#define NTILES ((NN + 127) / 128)   // 782
#define NB 512                      // scatter-carrying convert blocks
#define CHUNK (NE / NB)             // 3125
#define NBUCK ((NN + 255) / 256)    // 391 coarse buckets (dst>>8)
#define BCAP 4608                   // bucket capacity (mean 4096, +8 sigma)
#define QCAP 1536                   // quarter capacity (mean 1024, +16 sigma)

typedef __bf16 bf16x8 __attribute__((ext_vector_type(8)));
typedef float f32x4 __attribute__((ext_vector_type(4)));
typedef float f32x2 __attribute__((ext_vector_type(2)));

// round-to-nearest-even fp32 -> bf16, two at a time, packed into a uint
__device__ __forceinline__ unsigned int f2bf2(float a, float b) {
  union { float f; unsigned u; } x, y;
  x.f = a; y.f = b;
  unsigned ua = x.u + (0x7FFFu + ((x.u >> 16) & 1u));
  unsigned ub = y.u + (0x7FFFu + ((y.u >> 16) & 1u));
  return (ua >> 16) | (ub & 0xFFFF0000u);
}

// ---------------- 00. zero bucket cursors (workspace arrives poisoned) ------
__global__ __launch_bounds__(256) void zero_kernel(int* __restrict__ gcur) {
  int t = blockIdx.x * 256 + threadIdx.x;
  if (t < NBUCK) gcur[t] = 0;
}

// ---------------- 0+A. convert + (blocks < NB) coarse scatter ---------------
// All 6250 blocks: h rows b*16..b*16+15 -> h8 (fp8) + hbf (bf16 fragment
// order). Blocks < NB additionally bucket-scatter their 3125-edge chunk into
// ebuf (LDS hist + scan + one atomic reservation per bucket + burst write).
// The two jobs are independent; convert is BW-bound, scatter LDS-bound ->
// they overlap instead of serializing as two launches.
__global__ __launch_bounds__(256) void convert_scatter_kernel(
    const float4* __restrict__ hp, uint2* __restrict__ h8,
    uint4* __restrict__ hbf, const int* __restrict__ src,
    const int* __restrict__ dst, int* __restrict__ gcur,
    unsigned* __restrict__ ebuf) {
  __shared__ int lhp[512];
  __shared__ int lbase[NBUCK];
  __shared__ int lcur[NBUCK];
  __shared__ int gstart[NBUCK];
  __shared__ unsigned sdata[CHUNK];
  __shared__ int sgpos[CHUNK];
  int t = threadIdx.x, b = blockIdx.x;
  int gid = b * 256 + t;                       // 1.6M threads, 8 floats each
  float4 a = hp[2 * gid], c = hp[2 * gid + 1];
  int lo = __builtin_amdgcn_cvt_pk_fp8_f32(a.x, a.y, 0, false);
  lo = __builtin_amdgcn_cvt_pk_fp8_f32(a.z, a.w, lo, true);
  int hi = __builtin_amdgcn_cvt_pk_fp8_f32(c.x, c.y, 0, false);
  hi = __builtin_amdgcn_cvt_pk_fp8_f32(c.z, c.w, hi, true);
  h8[gid] = make_uint2((unsigned)lo, (unsigned)hi);

  uint4 q;
  q.x = f2bf2(a.x, a.y);
  q.y = f2bf2(a.z, a.w);
  q.z = f2bf2(c.x, c.y);
  q.w = f2bf2(c.z, c.w);
  int m = t >> 4, c8 = t & 15;
  int rt = b & 7, kc = c8 >> 2, quad = c8 & 3;
  hbf[(size_t)(b >> 3) * 2048 + (((rt << 2) + kc) << 6) + (quad << 4) + m] = q;

  if (b >= NB) return;   // block-uniform: __syncthreads below is safe

  lhp[t] = 0;
  lhp[t + 256] = 0;
  __syncthreads();
  int e0 = b * CHUNK;
  for (int e = e0 + t; e < e0 + CHUNK; e += 256)
    atomicAdd(&lhp[dst[e] >> 8], 1);
  __syncthreads();
  int c0 = lhp[t], c1 = lhp[t + 256];
  for (int d = 1; d < 512; d <<= 1) {
    int x0 = (t >= d) ? lhp[t - d] : 0;
    int x1 = ((t + 256) >= d) ? lhp[t + 256 - d] : 0;
    __syncthreads();
    lhp[t] += x0;
    lhp[t + 256] += x1;
    __syncthreads();
  }
  if (t < NBUCK) {
    lbase[t] = lhp[t] - c0;
    lcur[t] = 0;
    gstart[t] = t * BCAP + (c0 ? atomicAdd(&gcur[t], c0) : 0);
  }
  int i2 = t + 256;
  if (i2 < NBUCK) {
    lbase[i2] = lhp[i2] - c1;
    lcur[i2] = 0;
    gstart[i2] = i2 * BCAP + (c1 ? atomicAdd(&gcur[i2], c1) : 0);
  }
  __syncthreads();
  for (int e = e0 + t; e < e0 + CHUNK; e += 256) {
    int d = dst[e], s = src[e];
    int bk = d >> 8;
    int slot = atomicAdd(&lcur[bk], 1);
    int lp = lbase[bk] + slot;
    sdata[lp] = ((unsigned)(d & 255) << 24) | (unsigned)s;
    sgpos[lp] = gstart[bk] + slot;
  }
  __syncthreads();
  for (int j = t; j < CHUNK; j += 256) ebuf[sgpos[j]] = sdata[j];
}

// ---------------- fp8 accumulate helper (packed f32x2 adds) -----------------
__device__ __forceinline__ void acc16p(f32x2* a, uint4 u) {
  a[0] += __builtin_amdgcn_cvt_pk_f32_fp8(u.x, false);
  a[1] += __builtin_amdgcn_cvt_pk_f32_fp8(u.x, true);
  a[2] += __builtin_amdgcn_cvt_pk_f32_fp8(u.y, false);
  a[3] += __builtin_amdgcn_cvt_pk_f32_fp8(u.y, true);
  a[4] += __builtin_amdgcn_cvt_pk_f32_fp8(u.z, false);
  a[5] += __builtin_amdgcn_cvt_pk_f32_fp8(u.z, true);
  a[6] += __builtin_amdgcn_cvt_pk_f32_fp8(u.w, false);
  a[7] += __builtin_amdgcn_cvt_pk_f32_fp8(u.w, true);
}

// ---------------- B+4. quarter-bucket: LDS sort + pipelined gather ----------
// 4 blocks per bucket, 64 nodes each. 8 blocks/CU (7KB LDS, <=64 VGPR) --
// occupancy is the latency-hiding lever; round-7's (256,4) cap was the
// bottleneck (31% occupancy, 70% stall).
__global__ __launch_bounds__(256, 8) void gather_bucket_kernel(
    const unsigned* __restrict__ ebuf, const int* __restrict__ gcur,
    const uint4* __restrict__ h8, uint4* __restrict__ hfrag) {
  __shared__ int hist[64], st[64], cur[64];
  __shared__ int ssort[QCAP];
  int t = threadIdx.x, bid = blockIdx.x;
  int g = bid >> 2, qt = bid & 3;
  int base = g * BCAP;
  int cnt = gcur[g];
  int lo = qt * 64;
  if (t < 64) hist[t] = 0;
  __syncthreads();
  // pass A: histogram own quarter's nodes (ebuf segment is L2-hot)
  for (int j = t; j < cnt; j += 256) {
    int dn = (int)(ebuf[base + j] >> 24) - lo;
    if ((unsigned)dn < 64u) atomicAdd(&hist[dn], 1);
  }
  __syncthreads();
  if (t < 64) st[t] = hist[t];
  __syncthreads();
  for (int d = 1; d < 64; d <<= 1) {
    int x = (t < 64 && t >= d) ? st[t - d] : 0;
    __syncthreads();
    if (t < 64) st[t] += x;
    __syncthreads();
  }
  if (t < 64) {
    int s = st[t] - hist[t];
    st[t] = s;
    cur[t] = s;
  }
  __syncthreads();
  // pass B: sort own edges into LDS
  for (int j = t; j < cnt; j += 256) {
    unsigned e = ebuf[base + j];
    int dn = (int)(e >> 24) - lo;
    if ((unsigned)dn < 64u) {
      int pos = atomicAdd(&cur[dn], 1);
      if (pos < QCAP) ssort[pos] = (int)(e & 0x00FFFFFFu);
    }
  }
  __syncthreads();
  // gather: 32 groups of 8 lanes; 2 rounds -> 64 nodes; depth-2 pipeline
  int grp = t >> 3, l = t & 7;
  uint4* bp = hfrag + (size_t)(bid >> 1) * 2048;
#pragma unroll 1
  for (int rnd = 0; rnd < 2; rnd++) {
    int li = rnd * 32 + grp;          // local node 0..63
    int deg = hist[li];
    int j0 = st[li];
    f32x2 a[8];
#pragma unroll
    for (int i = 0; i < 8; i++) a[i] = f32x2{0.f, 0.f};
    int jmax = deg & ~3;
    if (jmax > 0) {
      int s0 = ssort[j0], s1 = ssort[j0 + 1], s2 = ssort[j0 + 2], s3 = ssort[j0 + 3];
      uint4 u0 = h8[(size_t)s0 * 8 + l];
      uint4 u1 = h8[(size_t)s1 * 8 + l];
      uint4 u2 = h8[(size_t)s2 * 8 + l];
      uint4 u3 = h8[(size_t)s3 * 8 + l];
      for (int j4 = 4; j4 < jmax; j4 += 4) {
        int t0 = ssort[j0 + j4], t1 = ssort[j0 + j4 + 1];
        int t2 = ssort[j0 + j4 + 2], t3 = ssort[j0 + j4 + 3];
        uint4 v0 = h8[(size_t)t0 * 8 + l];
        uint4 v1 = h8[(size_t)t1 * 8 + l];
        uint4 v2 = h8[(size_t)t2 * 8 + l];
        uint4 v3 = h8[(size_t)t3 * 8 + l];
        acc16p(a, u0); acc16p(a, u1); acc16p(a, u2); acc16p(a, u3);
        u0 = v0; u1 = v1; u2 = v2; u3 = v3;
      }
      acc16p(a, u0); acc16p(a, u1); acc16p(a, u2); acc16p(a, u3);
    }
    for (int j2 = jmax; j2 < deg; j2++) acc16p(a, h8[(size_t)ssort[j0 + j2] * 8 + l]);
    float sc = (deg > 0) ? (1.0f / (float)deg) : 0.0f;
    f32x2 s2 = {sc, sc};
#pragma unroll
    for (int i = 0; i < 8; i++) a[i] *= s2;
    uint4 r0, r1;
    r0.x = f2bf2(a[0].x, a[0].y);  r0.y = f2bf2(a[1].x, a[1].y);
    r0.z = f2bf2(a[2].x, a[2].y);  r0.w = f2bf2(a[3].x, a[3].y);
    r1.x = f2bf2(a[4].x, a[4].y);  r1.y = f2bf2(a[5].x, a[5].y);
    r1.z = f2bf2(a[6].x, a[6].y);  r1.w = f2bf2(a[7].x, a[7].y);
    int r = ((qt & 1) << 6) + li;     // row within 128-row tile
    int rt = r >> 4, m = r & 15;
    int kc = l >> 1, quad = (l & 1) << 1;
    int slot = (((rt << 2) + kc) << 6) + (quad << 4) + m;
    bp[slot] = r0;
    bp[slot + 16] = r1;
  }
}

// ---------------- W staging into fragment-linear LDS ------------------------
__device__ __forceinline__ void stage_w(const float* __restrict__ X,
                                        uint4* buf, int t) {
#pragma unroll
  for (int i = 0; i < 8; i++) {
    int id = t + (i << 8);     // 0..2047
    int r = id >> 4;           // 0..127
    int c8 = id & 15;          // 0..15
    const float4* p = (const float4*)(X + (size_t)r * DD + (c8 << 3));
    float4 v0 = p[0], v1 = p[1];
    uint4 q;
    q.x = f2bf2(v0.x, v0.y);
    q.y = f2bf2(v0.z, v0.w);
    q.z = f2bf2(v1.x, v1.y);
    q.w = f2bf2(v1.z, v1.w);
    int rt = r >> 4, m = r & 15, kc = c8 >> 2, quad = c8 & 3;
    buf[(((rt << 2) + kc) << 6) + (quad << 4) + m] = q;
  }
}

__device__ __forceinline__ void compute_reg(const uint4* a, const uint4* sWb,
                                            f32x4 acc[2][8], int lane) {
#pragma unroll
  for (int kc = 0; kc < 4; kc++) {
    bf16x8 bfr[8];
#pragma unroll
    for (int n = 0; n < 8; n++)
      bfr[n] = *(const bf16x8*)&sWb[(((n << 2) + kc) << 6) + lane];
    bf16x8 a0 = *(const bf16x8*)&a[kc];
    bf16x8 a1 = *(const bf16x8*)&a[4 + kc];
#pragma unroll
    for (int n = 0; n < 8; n++) {
      acc[0][n] = __builtin_amdgcn_mfma_f32_16x16x32_bf16(a0, bfr[n], acc[0][n], 0, 0, 0);
      acc[1][n] = __builtin_amdgcn_mfma_f32_16x16x32_bf16(a1, bfr[n], acc[1][n], 0, 0, 0);
    }
  }
}

// ---------------- 5. out = h@Ws^T + hneigh@Wn^T + b -------------------------
// Both A operands fragment-ordered in HBM -> registers. Single 32KB sW buffer
// staged twice (Wself, then Wneigh) -> 4 blocks/CU.
__global__ __launch_bounds__(256, 4) void gemm_kernel(
    const uint4* __restrict__ hbf, const uint4* __restrict__ hfrag,
    const float* __restrict__ Wself, const float* __restrict__ Wneigh,
    const float* __restrict__ bias, float* __restrict__ out) {
  __shared__ uint4 sW[2048];   // 32 KB
  int t = threadIdx.x;
  int wv = t >> 6;
  int lane = t & 63;
  int row0 = blockIdx.x * 128;

  const uint4* fb1 = hbf + (size_t)blockIdx.x * 2048;
  const uint4* fb2 = hfrag + (size_t)blockIdx.x * 2048;
  uint4 a1[8], a2[8];
#pragma unroll
  for (int kc = 0; kc < 4; kc++) {
    int s0 = ((((wv * 2 + 0) << 2) + kc) << 6) + lane;
    int s1 = ((((wv * 2 + 1) << 2) + kc) << 6) + lane;
    a1[kc] = fb1[s0]; a1[4 + kc] = fb1[s1];
    a2[kc] = fb2[s0]; a2[4 + kc] = fb2[s1];
  }

  f32x4 acc[2][8];
#pragma unroll
  for (int i = 0; i < 2; i++)
#pragma unroll
    for (int n = 0; n < 8; n++) acc[i][n] = f32x4{0.f, 0.f, 0.f, 0.f};

  stage_w(Wself, sW, t);
  __syncthreads();
  compute_reg(a1, sW, acc, lane);
  __syncthreads();
  stage_w(Wneigh, sW, t);
  __syncthreads();
  compute_reg(a2, sW, acc, lane);

  // epilogue: + bias (C/D layout: col=lane&15, row=(lane>>4)*4+reg)
  int col = lane & 15, rq = lane >> 4;
  float bv[8];
#pragma unroll
  for (int n = 0; n < 8; n++) bv[n] = bias[n * 16 + col];
#pragma unroll
  for (int rt = 0; rt < 2; rt++) {
    int rb = row0 + (wv * 2 + rt) * 16 + rq * 4;
#pragma unroll
    for (int r = 0; r < 4; r++) {
      int row = rb + r;
      if (row < NN) {
        float* op = out + (size_t)row * DD + col;
#pragma unroll
        for (int n = 0; n < 8; n++) op[n * 16] = acc[rt][n][r] + bv[n];
      }
    }
  }
}

extern "C" void kernel_launch(void* const* d_in, const int* in_sizes, int n_in,
                              void* d_out, int out_size, void* d_ws, size_t ws_size,
                              hipStream_t stream) {
  const float* h      = (const float*)d_in[0];
  const int*   src    = (const int*)d_in[1];
  const int*   dst    = (const int*)d_in[2];
  const float* Wself  = (const float*)d_in[3];
  const float* Wneigh = (const float*)d_in[4];
  const float* bias   = (const float*)d_in[5];
  float* out = (float*)d_out;

  // workspace layout (bytes); peak footprint ~71.3 MB
  char* ws = (char*)d_ws;
  unsigned* h8       = (unsigned*)ws;                     // 12,800,000
  unsigned* hbf      = (unsigned*)(ws + 12800000);        // 25,624,576 (782*32768)
  unsigned* hfrag    = (unsigned*)(ws + 38424576);        // 25,624,576
  unsigned* ebuf     = (unsigned*)(ws + 64049152);        //  7,206,912 (391*4608*4)
  int*      gcur     = (int*)(ws + 71256064);             //      1,564

  zero_kernel<<<2, 256, 0, stream>>>(gcur);
  convert_scatter_kernel<<<6250, 256, 0, stream>>>((const float4*)h, (uint2*)h8,
                                                   (uint4*)hbf, src, dst, gcur,
                                                   ebuf);
  gather_bucket_kernel<<<NBUCK * 4, 256, 0, stream>>>(ebuf, gcur,
                                                      (const uint4*)h8,
                                                      (uint4*)hfrag);
  gemm_kernel<<<NTILES, 256, 0, stream>>>((const uint4*)hbf, (const uint4*)hfrag,
                                          Wself, Wneigh, bias, out);
}